// Round 1
// baseline (1416.474 us; speedup 1.0000x reference)
//
#include <hip/hip_runtime.h>
#include <hip/hip_bf16.h>
#include <math.h>

#define D_  1024
#define B_  32
#define T_  2048
#define L_  8
#define P_  720
#define E_  16
#define BP_ (B_*P_)   /* 23040 */

// ---- workspace layout (float offsets) ----
#define OFF_STEPB   ((size_t)0)        // [720][1024]
#define OFF_CKWT    ((size_t)737280)   // ctx_k_w^T  [1024][1024]
#define OFF_SQWT    ((size_t)1785856)  // step_q_w^T [1024][1024]
#define OFF_EXPS    ((size_t)2834432)  // [B][T][8] exp(S)
#define OFF_ATTW    ((size_t)3358720)  // [B][P][8] attn2 weights
#define OFF_LOGITP  ((size_t)3543040)  // [4][B*P][16] logit partials
// ---- memset (atomic-accumulate) region starts here ----
#define OFF_Q1      ((size_t)5017600)  // [8][1024]
#define OFF_Q1P     ((size_t)5025792)  // [8][1024]
#define OFF_NUM     ((size_t)5033984)  // [B][L][1024] softmax numerator
#define OFF_TMP1    ((size_t)5296128)  // [256][1024]
#define OFF_LATCTX  ((size_t)5558272)
#define OFF_K2      ((size_t)5820416)
#define OFF_V2      ((size_t)6082560)
#define OFF_K2P     ((size_t)6344704)
#define OFF_V2A     ((size_t)6606848)
#define OFF_V2P     ((size_t)6868992)
#define OFF_SB1     ((size_t)7131136)  // [720][1024]
// ---- memset region ends here ----
#define OFF_DENR    ((size_t)7868416)  // [256] 1/denominator
#define WS_FLOATS   ((size_t)7868672)  // ~31.5 MB

__device__ __forceinline__ float gelu_exact(float x){
    return 0.5f * x * (1.0f + erff(x * 0.70710678118654752f));
}

// step_base[p][d] = query_pos[p][d] + pred_len_table[720][d]
__global__ void k_stepb(const float* __restrict__ qpos, const float* __restrict__ plt,
                        float* __restrict__ stepb){
    int p = blockIdx.x;
    int d = threadIdx.x * 4;
    float4 a = *(const float4*)(qpos + (size_t)p*D_ + d);
    float4 b = *(const float4*)(plt  + (size_t)P_*D_ + d);
    a.x += b.x; a.y += b.y; a.z += b.z; a.w += b.w;
    *(float4*)(stepb + (size_t)p*D_ + d) = a;
}

// transpose two 1024x1024 weights (z selects which)
__global__ void k_transpose(const float* __restrict__ s0, const float* __restrict__ s1,
                            float* __restrict__ d0, float* __restrict__ d1){
    __shared__ float tile[32][33];
    const float* src = blockIdx.z ? s1 : s0;
    float*       dst = blockIdx.z ? d1 : d0;
    int tx = threadIdx.x & 31, ty = threadIdx.x >> 5;
    int bx = blockIdx.x * 32, by = blockIdx.y * 32;
    #pragma unroll
    for (int r = 0; r < 4; r++)
        tile[ty + 8*r][tx] = src[(size_t)(by + ty + 8*r)*D_ + bx + tx];
    __syncthreads();
    #pragma unroll
    for (int r = 0; r < 4; r++)
        dst[(size_t)(bx + ty + 8*r)*D_ + by + tx] = tile[tx][ty + 8*r];
}

// C[M,1024] (+)= rowscale * A[M,1024(chunk)] @ B[1024(chunk),1024]; split-K via gridDim.z, atomic epilogue.
// A rows read as scalar (uniform) loads; B columns coalesced per-lane.
__global__ void k_gemm(const float* __restrict__ A, const float* __restrict__ B,
                       float* __restrict__ C, int M, const float* __restrict__ rowscale){
    int n  = blockIdx.y * 256 + threadIdx.x;
    int kc = D_ / gridDim.z;
    int k0 = blockIdx.z * kc;
    int mb = blockIdx.x * 16;
    float acc[16];
    #pragma unroll
    for (int m = 0; m < 16; m++) acc[m] = 0.f;
    for (int k = k0; k < k0 + kc; k += 4){
        float b0 = B[(size_t)(k+0)*D_ + n];
        float b1 = B[(size_t)(k+1)*D_ + n];
        float b2 = B[(size_t)(k+2)*D_ + n];
        float b3 = B[(size_t)(k+3)*D_ + n];
        #pragma unroll
        for (int m = 0; m < 16; m++){
            int row = mb + m; if (row > M - 1) row = M - 1;   // uniform clamp, result discarded
            const float4 av = *(const float4*)(A + (size_t)row*D_ + k);
            acc[m] += av.x*b0 + av.y*b1 + av.z*b2 + av.w*b3;
        }
    }
    #pragma unroll
    for (int m = 0; m < 16; m++){
        int row = mb + m;
        if (row < M){
            float v = acc[m];
            if (rowscale) v *= rowscale[row];
            atomicAdd(C + (size_t)row*D_ + n, v);
        }
    }
}

// expS[b][t][l] = exp( dot(q1'[l], ctx[b,t]) / 32 ).  Thread-per-row, q1' via scalar loads.
__global__ void k_pass_a(const float* __restrict__ ctx, const float* __restrict__ q1p,
                         float* __restrict__ expS){
    int r = blockIdx.x * 64 + threadIdx.x;       // [0, B*T)
    const float4* cp = (const float4*)(ctx + (size_t)r * D_);
    float acc[8] = {0,0,0,0,0,0,0,0};
    #pragma unroll 4
    for (int d4 = 0; d4 < 256; d4++){
        float4 c = cp[d4];
        #pragma unroll
        for (int l = 0; l < 8; l++){
            const float4 q = *(const float4*)(q1p + (size_t)l*D_ + 4*d4);  // uniform -> s_load
            acc[l] += c.x*q.x + c.y*q.y + c.z*q.z + c.w*q.w;
        }
    }
    // |S| <= ~0.05 for these inputs: softmax without max-subtraction is exact-equivalent
    float4 e0, e1;
    e0.x = __expf(acc[0]*0.03125f); e0.y = __expf(acc[1]*0.03125f);
    e0.z = __expf(acc[2]*0.03125f); e0.w = __expf(acc[3]*0.03125f);
    e1.x = __expf(acc[4]*0.03125f); e1.y = __expf(acc[5]*0.03125f);
    e1.z = __expf(acc[6]*0.03125f); e1.w = __expf(acc[7]*0.03125f);
    *(float4*)(expS + (size_t)r*8)     = e0;
    *(float4*)(expS + (size_t)r*8 + 4) = e1;
}

// denr[b*8+l] = 1 / sum_t expS[b][t][l]
__global__ void k_pass_b(const float* __restrict__ expS, float* __restrict__ denr){
    __shared__ float red[256];
    int rr = blockIdx.x;            // b*8+l
    int b = rr >> 3, l = rr & 7;
    const float* base = expS + (size_t)b * T_ * 8 + l;
    float s = 0.f;
    #pragma unroll
    for (int j = 0; j < 8; j++) s += base[(size_t)(threadIdx.x + 256*j) * 8];
    red[threadIdx.x] = s;
    __syncthreads();
    for (int st = 128; st > 0; st >>= 1){
        if (threadIdx.x < st) red[threadIdx.x] += red[threadIdx.x + st];
        __syncthreads();
    }
    if (threadIdx.x == 0) denr[rr] = 1.0f / red[0];
}

// num[b][l][d] += sum_{t in chunk} expS[b][t][l] * ctx[b][t][d]
__global__ void k_pass_c(const float* __restrict__ ctx, const float* __restrict__ expS,
                         float* __restrict__ num){
    int b = blockIdx.x, ts = blockIdx.y;
    int d = threadIdx.x * 4;
    int t0 = ts * 128;
    float4 acc[8];
    #pragma unroll
    for (int l = 0; l < 8; l++) acc[l] = make_float4(0,0,0,0);
    for (int t = t0; t < t0 + 128; t++){
        float4 c = *(const float4*)(ctx + ((size_t)(b*T_ + t))*D_ + d);
        const float* ep = expS + ((size_t)(b*T_ + t))*8;   // uniform -> s_load
        #pragma unroll
        for (int l = 0; l < 8; l++){
            float e = ep[l];
            acc[l].x += e*c.x; acc[l].y += e*c.y; acc[l].z += e*c.z; acc[l].w += e*c.w;
        }
    }
    #pragma unroll
    for (int l = 0; l < 8; l++){
        float* np_ = num + ((size_t)(b*8 + l))*D_ + d;
        atomicAdd(np_+0, acc[l].x); atomicAdd(np_+1, acc[l].y);
        atomicAdd(np_+2, acc[l].z); atomicAdd(np_+3, acc[l].w);
    }
}

// attn2 logits + softmax over L=8, thread-per-p:  attw[b][p][l]
__global__ void k_f1(const float* __restrict__ stepb, const float* __restrict__ k2p,
                     float* __restrict__ attw){
    int b = blockIdx.y;
    int p = blockIdx.x * 64 + threadIdx.x;
    if (p >= P_) return;
    const float4* sp = (const float4*)(stepb + (size_t)p * D_);
    const float* kp = k2p + (size_t)b * 8 * D_;
    float acc[8] = {0,0,0,0,0,0,0,0};
    #pragma unroll 2
    for (int d4 = 0; d4 < 256; d4++){
        float4 s = sp[d4];
        #pragma unroll
        for (int l = 0; l < 8; l++){
            const float4 kv = *(const float4*)(kp + (size_t)l*D_ + 4*d4);  // uniform -> s_load
            acc[l] += s.x*kv.x + s.y*kv.y + s.z*kv.z + s.w*kv.w;
        }
    }
    float s8[8];
    #pragma unroll
    for (int l = 0; l < 8; l++) s8[l] = acc[l] * 0.03125f;
    float m = s8[0];
    #pragma unroll
    for (int l = 1; l < 8; l++) m = fmaxf(m, s8[l]);
    float e8[8]; float sum = 0.f;
    #pragma unroll
    for (int l = 0; l < 8; l++){ e8[l] = __expf(s8[l] - m); sum += e8[l]; }
    float inv = 1.0f / sum;
    float4 o0 = make_float4(e8[0]*inv, e8[1]*inv, e8[2]*inv, e8[3]*inv);
    float4 o1 = make_float4(e8[4]*inv, e8[5]*inv, e8[6]*inv, e8[7]*inv);
    size_t bp = (size_t)b * P_ + p;
    *(float4*)(attw + bp*8)     = o0;
    *(float4*)(attw + bp*8 + 4) = o1;
}

// pre->gelu->logit partials over a d-quarter. Thread-per-p; weights via uniform s_loads.
__global__ void k_f2(const float* __restrict__ SB1, const float* __restrict__ v2p,
                     const float* __restrict__ attw, const float* __restrict__ b1,
                     const float* __restrict__ w2, float* __restrict__ logitp){
    int b  = blockIdx.x;
    int p  = blockIdx.y * 64 + threadIdx.x;
    int dq = blockIdx.z;
    if (p >= P_) return;
    size_t bp = (size_t)b * P_ + p;
    float a[8];
    {
        float4 a0 = *(const float4*)(attw + bp*8);
        float4 a1 = *(const float4*)(attw + bp*8 + 4);
        a[0]=a0.x; a[1]=a0.y; a[2]=a0.z; a[3]=a0.w;
        a[4]=a1.x; a[5]=a1.y; a[6]=a1.z; a[7]=a1.w;
    }
    float acc16[16];
    #pragma unroll
    for (int e = 0; e < 16; e++) acc16[e] = 0.f;
    const float* sbp = SB1 + (size_t)p * D_;
    int dbase = dq * 256;
    for (int dd = 0; dd < 256; dd += 4){
        int d = dbase + dd;
        float4 pre = *(const float4*)(sbp + d);
        float4 bb  = *(const float4*)(b1 + d);               // uniform
        pre.x += bb.x; pre.y += bb.y; pre.z += bb.z; pre.w += bb.w;
        #pragma unroll
        for (int l = 0; l < 8; l++){
            const float4 vv = *(const float4*)(v2p + ((size_t)(b*8 + l))*D_ + d);  // uniform
            pre.x += a[l]*vv.x; pre.y += a[l]*vv.y; pre.z += a[l]*vv.z; pre.w += a[l]*vv.w;
        }
        float h[4];
        h[0] = gelu_exact(pre.x); h[1] = gelu_exact(pre.y);
        h[2] = gelu_exact(pre.z); h[3] = gelu_exact(pre.w);
        #pragma unroll
        for (int i = 0; i < 4; i++){
            const float* w2r = w2 + (size_t)(d + i) * E_;    // uniform
            #pragma unroll
            for (int e = 0; e < 16; e++) acc16[e] += h[i] * w2r[e];
        }
    }
    float* outp = logitp + ((size_t)dq * BP_ + bp) * 16;
    #pragma unroll
    for (int e = 0; e < 16; e += 4){
        float4 v = make_float4(acc16[e], acc16[e+1], acc16[e+2], acc16[e+3]);
        *(float4*)(outp + e) = v;
    }
}

// top-2 + masked softmax + expert combine
__global__ void k_f3(const float* __restrict__ logitp, const float* __restrict__ b2,
                     const float* __restrict__ qe, float* __restrict__ out){
    int p = blockIdx.x, b = blockIdx.y;
    size_t bp = (size_t)b * P_ + p;
    float lg[16];
    #pragma unroll
    for (int e = 0; e < 16; e++){
        lg[e] = logitp[((size_t)0*BP_ + bp)*16 + e]
              + logitp[((size_t)1*BP_ + bp)*16 + e]
              + logitp[((size_t)2*BP_ + bp)*16 + e]
              + logitp[((size_t)3*BP_ + bp)*16 + e]
              + b2[e];
    }
    int e1 = 0; float l1 = lg[0];
    #pragma unroll
    for (int e = 1; e < 16; e++) if (lg[e] > l1){ l1 = lg[e]; e1 = e; }   // ties -> lowest idx
    int e2 = 0; float l2 = -1e30f;
    #pragma unroll
    for (int e = 0; e < 16; e++) if (e != e1 && lg[e] > l2){ l2 = lg[e]; e2 = e; }
    float q  = __expf(l2 - l1);
    float w1 = 1.0f / (1.0f + q);
    float w2 = q / (1.0f + q);
    int d = threadIdx.x * 4;
    float4 x1 = *(const float4*)(qe + ((size_t)e1 * P_ + p)*D_ + d);
    float4 x2 = *(const float4*)(qe + ((size_t)e2 * P_ + p)*D_ + d);
    float4 o;
    o.x = w1*x1.x + w2*x2.x; o.y = w1*x1.y + w2*x2.y;
    o.z = w1*x1.z + w2*x2.z; o.w = w1*x1.w + w2*x2.w;
    *(float4*)(out + bp*D_ + d) = o;
}

extern "C" void kernel_launch(void* const* d_in, const int* in_sizes, int n_in,
                              void* d_out, int out_size, void* d_ws, size_t ws_size,
                              hipStream_t stream) {
    (void)in_sizes; (void)n_in; (void)out_size; (void)ws_size;
    const float* ctx  = (const float*)d_in[0];
    const float* qexp = (const float*)d_in[1];
    const float* qpos = (const float*)d_in[2];
    const float* plt  = (const float*)d_in[3];
    const float* lats = (const float*)d_in[4];
    const float* w_lq = (const float*)d_in[5];
    const float* w_ck = (const float*)d_in[6];
    const float* w_cv = (const float*)d_in[7];
    const float* w_lo = (const float*)d_in[8];
    const float* w_sq = (const float*)d_in[9];
    const float* w_lk = (const float*)d_in[10];
    const float* w_lv = (const float*)d_in[11];
    const float* w_so = (const float*)d_in[12];
    const float* w_g1 = (const float*)d_in[13];
    const float* b_g1 = (const float*)d_in[14];
    const float* w_g2 = (const float*)d_in[15];
    const float* b_g2 = (const float*)d_in[16];
    float* out = (float*)d_out;
    float* ws  = (float*)d_ws;

    float* stepb  = ws + OFF_STEPB;
    float* ckwT   = ws + OFF_CKWT;
    float* sqwT   = ws + OFF_SQWT;
    float* expS   = ws + OFF_EXPS;
    float* attw   = ws + OFF_ATTW;
    float* logitp = ws + OFF_LOGITP;
    float* q1     = ws + OFF_Q1;
    float* q1p    = ws + OFF_Q1P;
    float* num    = ws + OFF_NUM;
    float* tmp1   = ws + OFF_TMP1;
    float* latctx = ws + OFF_LATCTX;
    float* k2     = ws + OFF_K2;
    float* v2     = ws + OFF_V2;
    float* k2p    = ws + OFF_K2P;
    float* v2a    = ws + OFF_V2A;
    float* v2p    = ws + OFF_V2P;
    float* SB1    = ws + OFF_SB1;
    float* denr   = ws + OFF_DENR;

    // zero the atomic-accumulate region
    hipMemsetAsync(q1, 0, (OFF_DENR - OFF_Q1) * sizeof(float), stream);

    k_stepb<<<dim3(P_), dim3(256), 0, stream>>>(qpos, plt, stepb);
    k_transpose<<<dim3(32,32,2), dim3(256), 0, stream>>>(w_ck, w_sq, ckwT, sqwT);

    // q1 = latents @ lat_q_w ; q1' = q1 @ ctx_k_w^T
    k_gemm<<<dim3(1,4,8),  dim3(256), 0, stream>>>(lats, w_lq, q1,  8,  nullptr);
    k_gemm<<<dim3(1,4,8),  dim3(256), 0, stream>>>(q1,   ckwT, q1p, 8,  nullptr);

    // stage 1 attention over ctx (2 passes over 268MB)
    k_pass_a<<<dim3((B_*T_)/64), dim3(64), 0, stream>>>(ctx, q1p, expS);
    k_pass_b<<<dim3(B_*L_), dim3(256), 0, stream>>>(expS, denr);
    k_pass_c<<<dim3(B_,16), dim3(256), 0, stream>>>(ctx, expS, num);

    // lat_ctx = ((P@ctx) @ Wv) @ Wo ; then k2/v2 chain
    k_gemm<<<dim3(16,4,4), dim3(256), 0, stream>>>(num,    w_cv, tmp1,   256, denr);
    k_gemm<<<dim3(16,4,4), dim3(256), 0, stream>>>(tmp1,   w_lo, latctx, 256, nullptr);
    k_gemm<<<dim3(16,4,4), dim3(256), 0, stream>>>(latctx, w_lk, k2,     256, nullptr);
    k_gemm<<<dim3(16,4,4), dim3(256), 0, stream>>>(latctx, w_lv, v2,     256, nullptr);
    k_gemm<<<dim3(16,4,4), dim3(256), 0, stream>>>(k2,     sqwT, k2p,    256, nullptr);
    k_gemm<<<dim3(16,4,4), dim3(256), 0, stream>>>(v2,     w_so, v2a,    256, nullptr);
    k_gemm<<<dim3(16,4,4), dim3(256), 0, stream>>>(v2a, w_g1 + (size_t)D_*D_, v2p, 256, nullptr);

    // SB1 = step_base @ gate_w1[:1024]  (split-K 8 for accuracy + parallelism)
    k_gemm<<<dim3(45,4,8), dim3(256), 0, stream>>>(stepb, w_g1, SB1, P_, nullptr);

    // gating
    k_f1<<<dim3(12, B_),    dim3(64),  0, stream>>>(stepb, k2p, attw);
    k_f2<<<dim3(B_, 12, 4), dim3(64),  0, stream>>>(SB1, v2p, attw, b_g1, w_g2, logitp);
    k_f3<<<dim3(P_, B_),    dim3(256), 0, stream>>>(logitp, b_g2, qexp, out);
}